// Round 4
// baseline (177.740 us; speedup 1.0000x reference)
//
#include <hip/hip_runtime.h>
#include <hip/hip_bf16.h>

#define HH 512
#define WW 512
#define CIN 256
#define COUT 256
#define NPTS 65536
#define PW 514
#define NPIX (PW * PW)
#define NKT 72                      // K tiles of 32 (total K = 2304)

typedef __bf16 bf16x8 __attribute__((ext_vector_type(8)));
typedef float f32x16 __attribute__((ext_vector_type(16)));
typedef unsigned short us8 __attribute__((ext_vector_type(8)));

static __device__ __forceinline__ unsigned short f2bf(float f) {
  unsigned u = __builtin_bit_cast(unsigned, f);
  unsigned r = u + 0x7fffu + ((u >> 16) & 1u);
  return (unsigned short)(r >> 16);
}

static __device__ __forceinline__ void gload16(const void* g, void* l) {
  __builtin_amdgcn_global_load_lds(
      (const __attribute__((address_space(1))) unsigned int*)g,
      (__attribute__((address_space(3))) unsigned int*)l, 16, 0, 0);
}

// A layout: i = kt*8192 + o ; r = o>>5 (co), cp = (o>>3)&3, j = o&7,
// logical chunk c = cp ^ ((r>>1)&3), k = kt*32 + c*8 + j (k = t*256+ci).
// Linear global_load_lds of one 16 KB block -> swizzled LDS A-tile.
__global__ __launch_bounds__(256) void prep_weight(const float* __restrict__ w,
                                                   unsigned short* __restrict__ A) {
  int i = blockIdx.x * 256 + threadIdx.x;       // 72*8192 = 589824 total
  int kt = i >> 13;
  int o  = i & 8191;
  int r  = o >> 5;
  int cp = (o >> 3) & 3;
  int j  = o & 7;
  int c  = cp ^ ((r >> 1) & 3);
  int k  = kt * 32 + c * 8 + j;
  int t  = k >> 8;
  int ci = k & 255;
  A[i] = f2bf(w[r * 2304 + ci * 9 + t]);
}

// Zero the border ring of the padded (514x514) bf16 feature image.
__global__ __launch_bounds__(256) void border_zero(unsigned short* __restrict__ Ft) {
  int g = blockIdx.x * 256 + threadIdx.x;
  if (g >= 2052 * 32) return;
  int p = g >> 5, c = g & 31;
  int py, px;
  if (p < 514)        { py = 0;        px = p; }
  else if (p < 1028)  { py = 513;      px = p - 514; }
  else if (p < 1540)  { py = p - 1027; px = 0; }
  else                { py = p - 1539; px = 513; }
  *(us8*)&Ft[((size_t)py * PW + px) * 256 + c * 8] = (us8){0, 0, 0, 0, 0, 0, 0, 0};
}

// Ft[((y+1)*514 + (x+1))*256 + ci] = bf16(feature[ci][y][x])
__global__ __launch_bounds__(256) void transpose_feat(const float* __restrict__ f,
                                                      unsigned short* __restrict__ Ft) {
  __shared__ unsigned short lds[64 * 264];
  int pix0 = blockIdx.x * 64;
  int y = pix0 >> 9, x0 = pix0 & 511;
  int tid = threadIdx.x;
  int p = tid & 63;
  int cb = tid >> 6;
  const float* src = f + pix0 + p;
  for (int c8 = 0; c8 < 8; ++c8) {
    us8 v;
#pragma unroll
    for (int j = 0; j < 8; ++j) {
      int ci = cb * 64 + c8 * 8 + j;
      v[j] = f2bf(src[ci * 262144]);
    }
    *(us8*)&lds[p * 264 + cb * 64 + c8 * 8] = v;
  }
  __syncthreads();
  int cic = tid & 31;
  int pr = tid >> 5;
  for (int g = 0; g < 8; ++g) {
    int p2 = pr + g * 8;
    us8 v = *(const us8*)&lds[p2 * 264 + cic * 8];
    *(us8*)&Ft[((size_t)((y + 1) * PW + x0 + 1 + p2)) * 256 + cic * 8] = v;
  }
}

// 256x256xK gather-GEMM. BK=32, 4 LDS buffers, prefetch 3 K-tiles ahead,
// mfma_f32_32x32x16_bf16, 8 waves (2M x 4N), wave tile 128x64.
__global__ __launch_bounds__(512, 2) void gemm_gather(
    const unsigned short* __restrict__ A,     // prep'd, swizzle baked in
    const unsigned short* __restrict__ Ft,    // [514*514][256] bf16 padded
    const int* __restrict__ hidx,
    const int* __restrict__ widx,
    float* __restrict__ out) {
  __shared__ unsigned short lds[65536];       // A: 4 x 8192, B: 4 x 8192 shorts
  unsigned short* ldsB = lds + 32768;

  int tid = threadIdx.x;
  int lane = tid & 63, wv = tid >> 6;
  int wm = wv & 1, wn = wv >> 1;              // 2M x 4N wave grid
  int n0 = blockIdx.x << 8;

  // B staging: thread covers col c0 (pass0) and 128+c0 (pass1); physical
  // chunk pc = tid&3 holds logical chunk cc = pc ^ ((c0>>1)&3).
  int c0 = tid >> 2;
  int cc = (tid & 3) ^ ((tid >> 3) & 3);
  long pixA = (long)hidx[n0 + c0] * PW + widx[n0 + c0];
  long pixB = (long)hidx[n0 + 128 + c0] * PW + widx[n0 + 128 + c0];
  const unsigned short* FtB0 = Ft + pixA * 256 + cc * 8;
  const unsigned short* FtB1 = Ft + pixB * 256 + cc * 8;

#define STAGE_A(kt_)                                                          \
  do {                                                                        \
    const unsigned short* g_ = A + (size_t)(kt_) * 8192 + tid * 8;            \
    unsigned short* l_ = lds + ((kt_) & 3) * 8192 + tid * 8;                  \
    gload16(g_, l_);                                                          \
    gload16(g_ + 4096, l_ + 4096);                                            \
  } while (0)

#define STAGE_B(kt_)                                                          \
  do {                                                                        \
    int tp_ = (kt_) >> 3;                                                     \
    int q_ = tp_ / 3;                                                         \
    long off_ = (long)(q_ * PW + (tp_ - q_ * 3)) * 256 + ((kt_) & 7) * 32;    \
    unsigned short* l_ = ldsB + ((kt_) & 3) * 8192 + tid * 8;                 \
    gload16(FtB0 + off_, l_);                                                 \
    gload16(FtB1 + off_, l_ + 4096);                                          \
  } while (0)

#define LDA(dst, buf_, kg_, mt_)                                              \
  do {                                                                        \
    int r_ = wm * 128 + (mt_) * 32 + (lane & 31);                             \
    int c_ = ((kg_) * 2 + (lane >> 5)) ^ ((r_ >> 1) & 3);                     \
    dst = *(const bf16x8*)&lds[(buf_) * 8192 + r_ * 32 + c_ * 8];             \
  } while (0)

#define LDB(dst, buf_, kg_, nt_)                                              \
  do {                                                                        \
    int col_ = wn * 64 + (nt_) * 32 + (lane & 31);                            \
    int c_ = ((kg_) * 2 + (lane >> 5)) ^ ((col_ >> 1) & 3);                   \
    dst = *(const bf16x8*)&ldsB[(buf_) * 8192 + col_ * 32 + c_ * 8];          \
  } while (0)

#define MFMA8()                                                               \
  do {                                                                        \
    __builtin_amdgcn_s_setprio(1);                                            \
    acc[0][0] = __builtin_amdgcn_mfma_f32_32x32x16_bf16(af0, b0, acc[0][0], 0, 0, 0); \
    acc[0][1] = __builtin_amdgcn_mfma_f32_32x32x16_bf16(af0, b1, acc[0][1], 0, 0, 0); \
    acc[1][0] = __builtin_amdgcn_mfma_f32_32x32x16_bf16(af1, b0, acc[1][0], 0, 0, 0); \
    acc[1][1] = __builtin_amdgcn_mfma_f32_32x32x16_bf16(af1, b1, acc[1][1], 0, 0, 0); \
    acc[2][0] = __builtin_amdgcn_mfma_f32_32x32x16_bf16(af2, b0, acc[2][0], 0, 0, 0); \
    acc[2][1] = __builtin_amdgcn_mfma_f32_32x32x16_bf16(af2, b1, acc[2][1], 0, 0, 0); \
    acc[3][0] = __builtin_amdgcn_mfma_f32_32x32x16_bf16(af3, b0, acc[3][0], 0, 0, 0); \
    acc[3][1] = __builtin_amdgcn_mfma_f32_32x32x16_bf16(af3, b1, acc[3][1], 0, 0, 0); \
    __builtin_amdgcn_s_setprio(0);                                            \
  } while (0)

// One K-tile: phase 0 = k-group 0 (+stage A of kt+3), phase 1 = k-group 1
// (+stage B of kt+3, counted vmcnt WAITN_ draining tile kt+1's 4 loads).
#define TILE(kt_, DOSTAGE_, WAITN_)                                           \
  do {                                                                        \
    int buf_ = (kt_) & 3;                                                     \
    bf16x8 af0, af1, af2, af3, b0, b1;                                        \
    LDA(af0, buf_, 0, 0); LDA(af1, buf_, 0, 1);                               \
    LDA(af2, buf_, 0, 2); LDA(af3, buf_, 0, 3);                               \
    LDB(b0, buf_, 0, 0); LDB(b1, buf_, 0, 1);                                 \
    if (DOSTAGE_) STAGE_A((kt_) + 3);                                         \
    __builtin_amdgcn_s_barrier();                                             \
    MFMA8();                                                                  \
    __builtin_amdgcn_s_barrier();                                             \
    LDA(af0, buf_, 1, 0); LDA(af1, buf_, 1, 1);                               \
    LDA(af2, buf_, 1, 2); LDA(af3, buf_, 1, 3);                               \
    LDB(b0, buf_, 1, 0); LDB(b1, buf_, 1, 1);                                 \
    if (DOSTAGE_) STAGE_B((kt_) + 3);                                         \
    __builtin_amdgcn_s_barrier();                                             \
    MFMA8();                                                                  \
    if ((WAITN_) == 8) asm volatile("s_waitcnt vmcnt(8)" ::: "memory");       \
    else if ((WAITN_) == 4) asm volatile("s_waitcnt vmcnt(4)" ::: "memory");  \
    else if ((WAITN_) == 0) asm volatile("s_waitcnt vmcnt(0)" ::: "memory");  \
    __builtin_amdgcn_s_barrier();                                             \
  } while (0)

  f32x16 acc[4][2];
#pragma unroll
  for (int mt = 0; mt < 4; ++mt)
#pragma unroll
    for (int nt = 0; nt < 2; ++nt)
      acc[mt][nt] = (f32x16)(0.f);

  // Prologue: stage tiles 0,1,2 (12 loads); drain tile 0's 4 (vmcnt 8).
  STAGE_A(0); STAGE_B(0);
  STAGE_A(1); STAGE_B(1);
  STAGE_A(2); STAGE_B(2);
  asm volatile("s_waitcnt vmcnt(8)" ::: "memory");
  __builtin_amdgcn_s_barrier();

  for (int kt = 0; kt < NKT - 3; ++kt)   // kt = 0..68, stage kt+3, wait 8
    TILE(kt, 1, 8);
  TILE(69, 0, 4);
  TILE(70, 0, 0);
  TILE(71, 0, -1);

#undef STAGE_A
#undef STAGE_B
#undef LDA
#undef LDB
#undef MFMA8
#undef TILE

  // Epilogue: 32x32 C/D layout: col = lane&31, row = (r&3)+8*(r>>2)+4*(lane>>5)
  int colb = n0 + wn * 64 + (lane & 31);
  int rb = wm * 128 + ((lane >> 5) << 2);
#pragma unroll
  for (int mt = 0; mt < 4; ++mt)
#pragma unroll
    for (int nt = 0; nt < 2; ++nt)
#pragma unroll
      for (int r = 0; r < 16; ++r) {
        int row = rb + mt * 32 + (r & 3) + ((r >> 2) << 3);
        out[(size_t)row * NPTS + colb + nt * 32] = acc[mt][nt][r];
      }
}

// Safety-net path if workspace is too small: direct conv, fp32.
__global__ __launch_bounds__(256) void naive_conv(const float* __restrict__ f,
                                                  const float* __restrict__ w,
                                                  const int* __restrict__ hi,
                                                  const int* __restrict__ wi,
                                                  float* __restrict__ out) {
  int idx = blockIdx.x * 256 + threadIdx.x;
  int n = idx & (NPTS - 1);
  int co = idx >> 16;
  int bh = hi[n] - 1;
  int bw = wi[n] - 1;
  float acc = 0.f;
  for (int ci = 0; ci < CIN; ++ci) {
    const float* fc = f + (size_t)ci * 262144;
    const float* wc = w + (size_t)co * 2304 + ci * 9;
#pragma unroll
    for (int t = 0; t < 9; ++t) {
      int y = bh + t / 3, x = bw + t % 3;
      float v = (y >= 0 && y < 512 && x >= 0 && x < 512) ? fc[y * 512 + x] : 0.f;
      acc += wc[t] * v;
    }
  }
  out[(size_t)co * NPTS + n] = acc;
}

extern "C" void kernel_launch(void* const* d_in, const int* in_sizes, int n_in,
                              void* d_out, int out_size, void* d_ws, size_t ws_size,
                              hipStream_t stream) {
  const float* feature = (const float*)d_in[0];
  const float* weight  = (const float*)d_in[1];
  const int* hidx      = (const int*)d_in[2];
  const int* widx      = (const int*)d_in[3];
  float* out           = (float*)d_out;

  const size_t FT_OFF = 2ull * 1024 * 1024;
  const size_t FT_BYTES = (size_t)NPIX * 256 * 2;   // ~135 MiB
  const size_t NEED = FT_OFF + FT_BYTES;

  if (ws_size >= NEED) {
    unsigned short* Abf = (unsigned short*)d_ws;    // 1.125 MiB
    unsigned short* Ft = (unsigned short*)((char*)d_ws + FT_OFF);
    prep_weight<<<(NKT * 8192) / 256, 256, 0, stream>>>(weight, Abf);
    border_zero<<<(2052 * 32 + 255) / 256, 256, 0, stream>>>(Ft);
    transpose_feat<<<262144 / 64, 256, 0, stream>>>(feature, Ft);
    gemm_gather<<<NPTS / 256, 512, 0, stream>>>(Abf, Ft, hidx, widx, out);
  } else {
    naive_conv<<<(COUT * NPTS) / 256, 256, 0, stream>>>(feature, weight, hidx, widx, out);
  }
}

// Round 6
// 173.795 us; speedup vs baseline: 1.0227x; 1.0227x over previous
//
#include <hip/hip_runtime.h>
#include <hip/hip_bf16.h>

#define HH 512
#define WW 512
#define CIN 256
#define COUT 256
#define NPTS 65536
#define PW 514
#define NPIX (PW * PW)
#define NKT 72                      // K tiles of 32 (total K = 2304); 36 pairs

typedef __bf16 bf16x8 __attribute__((ext_vector_type(8)));
typedef float f32x16 __attribute__((ext_vector_type(16)));
typedef unsigned short us8 __attribute__((ext_vector_type(8)));

static __device__ __forceinline__ unsigned short f2bf(float f) {
  unsigned u = __builtin_bit_cast(unsigned, f);
  unsigned r = u + 0x7fffu + ((u >> 16) & 1u);
  return (unsigned short)(r >> 16);
}

static __device__ __forceinline__ void gload16(const void* g, void* l) {
  __builtin_amdgcn_global_load_lds(
      (const __attribute__((address_space(1))) unsigned int*)g,
      (__attribute__((address_space(3))) unsigned int*)l, 16, 0, 0);
}

// A layout (verified r2-r4): i = kt*8192 + o ; r = o>>5 (co),
// cp = (o>>3)&3, j = o&7, logical chunk c = cp ^ ((r>>1)&3),
// k = kt*32 + c*8 + j (k = t*256+ci). Linear 16KB DMA -> swizzled LDS tile.
__global__ __launch_bounds__(256) void prep_weight(const float* __restrict__ w,
                                                   unsigned short* __restrict__ A) {
  int i = blockIdx.x * 256 + threadIdx.x;       // 72*8192 = 589824 total
  int kt = i >> 13;
  int o  = i & 8191;
  int r  = o >> 5;
  int cp = (o >> 3) & 3;
  int j  = o & 7;
  int c  = cp ^ ((r >> 1) & 3);
  int k  = kt * 32 + c * 8 + j;
  int t  = k >> 8;
  int ci = k & 255;
  A[i] = f2bf(w[r * 2304 + ci * 9 + t]);
}

// Zero the border ring of the padded (514x514) bf16 feature image.
__global__ __launch_bounds__(256) void border_zero(unsigned short* __restrict__ Ft) {
  int g = blockIdx.x * 256 + threadIdx.x;
  if (g >= 2052 * 32) return;
  int p = g >> 5, c = g & 31;
  int py, px;
  if (p < 514)        { py = 0;        px = p; }
  else if (p < 1028)  { py = 513;      px = p - 514; }
  else if (p < 1540)  { py = p - 1027; px = 0; }
  else                { py = p - 1539; px = 513; }
  *(us8*)&Ft[((size_t)py * PW + px) * 256 + c * 8] = (us8){0, 0, 0, 0, 0, 0, 0, 0};
}

// Ft[((y+1)*514 + (x+1))*256 + ci] = bf16(feature[ci][y][x])
__global__ __launch_bounds__(256) void transpose_feat(const float* __restrict__ f,
                                                      unsigned short* __restrict__ Ft) {
  __shared__ unsigned short lds[64 * 264];
  int pix0 = blockIdx.x * 64;
  int y = pix0 >> 9, x0 = pix0 & 511;
  int tid = threadIdx.x;
  int p = tid & 63;
  int cb = tid >> 6;
  const float* src = f + pix0 + p;
  for (int c8 = 0; c8 < 8; ++c8) {
    us8 v;
#pragma unroll
    for (int j = 0; j < 8; ++j) {
      int ci = cb * 64 + c8 * 8 + j;
      v[j] = f2bf(src[ci * 262144]);
    }
    *(us8*)&lds[p * 264 + cb * 64 + c8 * 8] = v;
  }
  __syncthreads();
  int cic = tid & 31;
  int pr = tid >> 5;
  for (int g = 0; g < 8; ++g) {
    int p2 = pr + g * 8;
    us8 v = *(const us8*)&lds[p2 * 264 + cic * 8];
    *(us8*)&Ft[((size_t)((y + 1) * PW + x0 + 1 + p2)) * 256 + cic * 8] = v;
  }
}

// 256x256xK gather-GEMM. A: BK=32 x 3 bufs (48KB). B: 64-k pairs x 3 bufs
// (96KB), each pixel gathered as one 128B line. 1 barrier/tile, uniform
// vmcnt(6) counted waits (WAIT BEFORE BARRIER — cross-wave DMA visibility).
__global__ __launch_bounds__(512, 2) void gemm_gather(
    const unsigned short* __restrict__ A,     // prep'd, swizzle baked in
    const unsigned short* __restrict__ Ft,    // [514*514][256] bf16 padded
    const int* __restrict__ hidx,
    const int* __restrict__ widx,
    float* __restrict__ out) {
  __shared__ unsigned short lds[73728];       // A: 3*8192 @0, B: 3*16384 @24576
  unsigned short* ldsB = lds + 24576;

  int tid = threadIdx.x;
  int lane = tid & 63, wv = tid >> 6;
  int wm = wv & 1, wn = wv >> 1;
  int n0 = blockIdx.x << 8;

  // B gather: stage q covers cols [64q,64q+64); this thread col cq = 64q +
  // (tid>>3), phys chunk pc = tid&7 holds logical lc = pc ^ (cq&7).
  // 8 threads per pixel read one contiguous 128B (permuted 16B chunks).
  int lcB = (tid & 7) ^ ((tid >> 3) & 7);
  const unsigned short* FtQ0;
  const unsigned short* FtQ1;
  const unsigned short* FtQ2;
  const unsigned short* FtQ3;
  {
    int cq = tid >> 3;
    FtQ0 = Ft + (long)(hidx[n0 + cq] * PW + widx[n0 + cq]) * 256 + lcB * 8;
    FtQ1 = Ft + (long)(hidx[n0 + 64 + cq] * PW + widx[n0 + 64 + cq]) * 256 + lcB * 8;
    FtQ2 = Ft + (long)(hidx[n0 + 128 + cq] * PW + widx[n0 + 128 + cq]) * 256 + lcB * 8;
    FtQ3 = Ft + (long)(hidx[n0 + 192 + cq] * PW + widx[n0 + 192 + cq]) * 256 + lcB * 8;
  }

#define STAGE_A(t_, ab_)                                                      \
  do {                                                                        \
    const unsigned short* g_ = A + (size_t)(t_) * 8192 + tid * 8;             \
    unsigned short* l_ = lds + (ab_) * 8192 + tid * 8;                        \
    gload16(g_, l_);                                                          \
    gload16(g_ + 4096, l_ + 4096);                                            \
  } while (0)

// Pair p_: tap = p_>>2, ci0 = (p_&3)*64. 4 gloads, 128B/pixel contiguous.
#define STAGE_B(p_, bb_)                                                      \
  do {                                                                        \
    int tap_ = (p_) >> 2;                                                     \
    long off_ = (long)((tap_ / 3) * PW + (tap_ - (tap_ / 3) * 3)) * 256 +     \
                ((p_) & 3) * 64;                                              \
    unsigned short* l_ = ldsB + (bb_) * 16384 + tid * 8;                      \
    gload16(FtQ0 + off_, l_);                                                 \
    gload16(FtQ1 + off_, l_ + 4096);                                          \
    gload16(FtQ2 + off_, l_ + 8192);                                          \
    gload16(FtQ3 + off_, l_ + 12288);                                         \
  } while (0)

#define LDA(dst, ab_, kg_, mt_)                                               \
  do {                                                                        \
    int r_ = wm * 128 + (mt_) * 32 + (lane & 31);                             \
    int c_ = ((kg_) * 2 + (lane >> 5)) ^ ((r_ >> 1) & 3);                     \
    dst = *(const bf16x8*)&lds[(ab_) * 8192 + r_ * 32 + c_ * 8];              \
  } while (0)

#define LDB(dst, bb_, s_, kg_, nt_)                                           \
  do {                                                                        \
    int col_ = wn * 64 + (nt_) * 32 + (lane & 31);                            \
    int pc_ = ((s_) * 4 + (kg_) * 2 + (lane >> 5)) ^ (col_ & 7);              \
    dst = *(const bf16x8*)&ldsB[(bb_) * 16384 + col_ * 64 + pc_ * 8];         \
  } while (0)

#define MFMA8(a0, a1, a2, a3, b0, b1)                                         \
  do {                                                                        \
    __builtin_amdgcn_s_setprio(1);                                            \
    acc[0][0] = __builtin_amdgcn_mfma_f32_32x32x16_bf16(a0, b0, acc[0][0], 0, 0, 0); \
    acc[0][1] = __builtin_amdgcn_mfma_f32_32x32x16_bf16(a0, b1, acc[0][1], 0, 0, 0); \
    acc[1][0] = __builtin_amdgcn_mfma_f32_32x32x16_bf16(a1, b0, acc[1][0], 0, 0, 0); \
    acc[1][1] = __builtin_amdgcn_mfma_f32_32x32x16_bf16(a1, b1, acc[1][1], 0, 0, 0); \
    acc[2][0] = __builtin_amdgcn_mfma_f32_32x32x16_bf16(a2, b0, acc[2][0], 0, 0, 0); \
    acc[2][1] = __builtin_amdgcn_mfma_f32_32x32x16_bf16(a2, b1, acc[2][1], 0, 0, 0); \
    acc[3][0] = __builtin_amdgcn_mfma_f32_32x32x16_bf16(a3, b0, acc[3][0], 0, 0, 0); \
    acc[3][1] = __builtin_amdgcn_mfma_f32_32x32x16_bf16(a3, b1, acc[3][1], 0, 0, 0); \
    __builtin_amdgcn_s_setprio(0);                                            \
  } while (0)

// FIXED vs r5: per-wave waits (lgkm for my ds_reads, counted vmcnt for my
// DMA slice) come BEFORE s_barrier, so after the barrier ALL waves' slices
// of the tile are resident. r5 had barrier-then-vmcnt => cross-wave race.
#define HEAD(W_)                                                              \
  do {                                                                        \
    asm volatile("s_waitcnt lgkmcnt(0)" ::: "memory");                        \
    asm volatile("s_waitcnt vmcnt(" #W_ ")" ::: "memory");                    \
    __builtin_amdgcn_s_barrier();                                             \
    __builtin_amdgcn_sched_barrier(0);                                        \
  } while (0)

// One BK=32 tile: reads A[ab_], B[bb_] k-half s_; optional stages.
#define TILE_BODY(ab_, bb_, s_)                                               \
  bf16x8 xa0, xa1, xa2, xa3, xb0, xb1, ya0, ya1, ya2, ya3, yb0, yb1;          \
  LDA(xa0, ab_, 0, 0); LDA(xa1, ab_, 0, 1); LDA(xa2, ab_, 0, 2);              \
  LDA(xa3, ab_, 0, 3); LDB(xb0, bb_, s_, 0, 0); LDB(xb1, bb_, s_, 0, 1)

#define TILE_TAIL(ab_, bb_, s_)                                               \
  LDA(ya0, ab_, 1, 0); LDA(ya1, ab_, 1, 1); LDA(ya2, ab_, 1, 2);              \
  LDA(ya3, ab_, 1, 3); LDB(yb0, bb_, s_, 1, 0); LDB(yb1, bb_, s_, 1, 1);      \
  MFMA8(xa0, xa1, xa2, xa3, xb0, xb1);                                        \
  MFMA8(ya0, ya1, ya2, ya3, yb0, yb1)

  f32x16 acc[4][2];
#pragma unroll
  for (int mt = 0; mt < 4; ++mt)
#pragma unroll
    for (int nt = 0; nt < 2; ++nt)
      acc[mt][nt] = (f32x16)(0.f);

  // Prologue (deadline order): A(0), Bp(0), A(1), Bp(1)  -> 12 loads.
  STAGE_A(0, 0);
  STAGE_B(0, 0);
  STAGE_A(1, 1);
  STAGE_B(1, 1);

  int abE = 0, bbP = 0;                        // (2p)%3, p%3
  for (int p = 0; p < 34; ++p) {
    int abO = abE + 1; if (abO == 3) abO = 0;
    int abN = abO + 1; if (abN == 3) abN = 0;  // (2p+2)%3
    int bbN = bbP + 2; if (bbN >= 3) bbN -= 3; // (p+2)%3
    {  // even tile t=2p
      HEAD(6);
      TILE_BODY(abE, bbP, 0);
      STAGE_A(2 * p + 2, abN);
      STAGE_B(p + 2, bbN);
      TILE_TAIL(abE, bbP, 0);
    }
    {  // odd tile t=2p+1
      HEAD(6);
      TILE_BODY(abO, bbP, 1);
      STAGE_A(2 * p + 3, abE);                 // (2p+3)%3 == (2p)%3
      TILE_TAIL(abO, bbP, 1);
    }
    abE = abN;
    bbP = bbP + 1; if (bbP == 3) bbP = 0;
  }
  // p=34: abE=(68)%3=2, abO=0, abN=1, bbP=34%3=1
  {
    HEAD(6);
    TILE_BODY(2, 1, 0);
    STAGE_A(70, 1);
    TILE_TAIL(2, 1, 0);
  }
  {
    HEAD(2);
    TILE_BODY(0, 1, 1);
    STAGE_A(71, 2);
    TILE_TAIL(0, 1, 1);
  }
  // p=35: t70 reads A buf 70%3=1, t71 reads buf 2; B pair 35 in buf 2
  {
    HEAD(2);
    TILE_BODY(1, 2, 0);
    TILE_TAIL(1, 2, 0);
  }
  {
    HEAD(0);
    TILE_BODY(2, 2, 1);
    TILE_TAIL(2, 2, 1);
  }

#undef STAGE_A
#undef STAGE_B
#undef LDA
#undef LDB
#undef MFMA8
#undef HEAD
#undef TILE_BODY
#undef TILE_TAIL

  // Epilogue (verified): col = lane&31, row = (r&3)+8*(r>>2)+4*(lane>>5)
  int colb = n0 + wn * 64 + (lane & 31);
  int rb = wm * 128 + ((lane >> 5) << 2);
#pragma unroll
  for (int mt = 0; mt < 4; ++mt)
#pragma unroll
    for (int nt = 0; nt < 2; ++nt)
#pragma unroll
      for (int r = 0; r < 16; ++r) {
        int row = rb + mt * 32 + (r & 3) + ((r >> 2) << 3);
        out[(size_t)row * NPTS + colb + nt * 32] = acc[mt][nt][r];
      }
}

// Safety-net path if workspace is too small: direct conv, fp32.
__global__ __launch_bounds__(256) void naive_conv(const float* __restrict__ f,
                                                  const float* __restrict__ w,
                                                  const int* __restrict__ hi,
                                                  const int* __restrict__ wi,
                                                  float* __restrict__ out) {
  int idx = blockIdx.x * 256 + threadIdx.x;
  int n = idx & (NPTS - 1);
  int co = idx >> 16;
  int bh = hi[n] - 1;
  int bw = wi[n] - 1;
  float acc = 0.f;
  for (int ci = 0; ci < CIN; ++ci) {
    const float* fc = f + (size_t)ci * 262144;
    const float* wc = w + (size_t)co * 2304 + ci * 9;
#pragma unroll
    for (int t = 0; t < 9; ++t) {
      int y = bh + t / 3, x = bw + t % 3;
      float v = (y >= 0 && y < 512 && x >= 0 && x < 512) ? fc[y * 512 + x] : 0.f;
      acc += wc[t] * v;
    }
  }
  out[(size_t)co * NPTS + n] = acc;
}

extern "C" void kernel_launch(void* const* d_in, const int* in_sizes, int n_in,
                              void* d_out, int out_size, void* d_ws, size_t ws_size,
                              hipStream_t stream) {
  const float* feature = (const float*)d_in[0];
  const float* weight  = (const float*)d_in[1];
  const int* hidx      = (const int*)d_in[2];
  const int* widx      = (const int*)d_in[3];
  float* out           = (float*)d_out;

  const size_t FT_OFF = 2ull * 1024 * 1024;
  const size_t FT_BYTES = (size_t)NPIX * 256 * 2;   // ~135 MiB
  const size_t NEED = FT_OFF + FT_BYTES;

  if (ws_size >= NEED) {
    unsigned short* Abf = (unsigned short*)d_ws;    // 1.125 MiB
    unsigned short* Ft = (unsigned short*)((char*)d_ws + FT_OFF);
    prep_weight<<<(NKT * 8192) / 256, 256, 0, stream>>>(weight, Abf);
    border_zero<<<(2052 * 32 + 255) / 256, 256, 0, stream>>>(Ft);
    transpose_feat<<<262144 / 64, 256, 0, stream>>>(feature, Ft);
    gemm_gather<<<NPTS / 256, 512, 0, stream>>>(Abf, Ft, hidx, widx, out);
  } else {
    naive_conv<<<(COUT * NPTS) / 256, 256, 0, stream>>>(feature, weight, hidx, widx, out);
  }
}